// Round 1
// baseline (244.082 us; speedup 1.0000x reference)
//
#include <hip/hip_runtime.h>

typedef _Float16 half8 __attribute__((ext_vector_type(8)));
typedef _Float16 half2v __attribute__((ext_vector_type(2)));
typedef float float4v __attribute__((ext_vector_type(4)));

// ---- helpers ----
__device__ __forceinline__ float dot2acc(unsigned a, unsigned b, float c) {
#if __has_builtin(__builtin_amdgcn_fdot2)
  return __builtin_amdgcn_fdot2(__builtin_bit_cast(half2v, a), __builtin_bit_cast(half2v, b), c, false);
#else
  half2v ha = __builtin_bit_cast(half2v, a);
  half2v hb = __builtin_bit_cast(half2v, b);
  c += (float)ha[0] * (float)hb[0];
  c += (float)ha[1] * (float)hb[1];
  return c;
#endif
}
__device__ __forceinline__ unsigned hscale(unsigned a, float s) {
  half2v ha = __builtin_bit_cast(half2v, a);
  half2v r;
  r[0] = (_Float16)((float)ha[0] * s);
  r[1] = (_Float16)((float)ha[1] * s);
  return __builtin_bit_cast(unsigned, r);
}
__device__ __forceinline__ void gload_lds16(const void* g, void* l) {
  __builtin_amdgcn_global_load_lds((const __attribute__((address_space(1))) unsigned*)g,
                                   (__attribute__((address_space(3))) unsigned*)l, 16, 0, 0);
}

// ---- fp32 -> fp16 convert, all three tensors in one launch ----
__global__ void cvt_all(const float4* __restrict__ x, const float4* __restrict__ wqk,
                        const float4* __restrict__ wpj,
                        ushort4* __restrict__ x16, ushort4* __restrict__ wqk16,
                        ushort4* __restrict__ wpj16) {
  int b = blockIdx.x;
  const float4* s;
  ushort4* d;
  int i;
  if (b < 16384) { s = x; d = x16; i = b * 256 + threadIdx.x; }
  else if (b < 16512) { s = wqk; d = wqk16; i = (b - 16384) * 256 + threadIdx.x; }
  else { s = wpj; d = wpj16; i = (b - 16512) * 256 + threadIdx.x; }
  float4 v = s[i];
  _Float16 a = (_Float16)v.x, bb = (_Float16)v.y, c = (_Float16)v.z, e = (_Float16)v.w;
  ushort4 o;
  o.x = __builtin_bit_cast(unsigned short, a);
  o.y = __builtin_bit_cast(unsigned short, bb);
  o.z = __builtin_bit_cast(unsigned short, c);
  o.w = __builtin_bit_cast(unsigned short, e);
  d[i] = o;
}

// ---- GEMM1: qk = x16 @ wqk16^T, epilogue scatters to q16/k16 (b,h,t,yx,j) fp16 ----
__global__ __launch_bounds__(256, 2)
void gemm_qk(const _Float16* __restrict__ A, const _Float16* __restrict__ Bw,
             _Float16* __restrict__ qo, _Float16* __restrict__ ko) {
  __shared__ _Float16 Ash[4096];
  __shared__ _Float16 Bsh[4096];
  const int tid = threadIdx.x;
  const int lane = tid & 63, w = tid >> 6;
  const int wm = w >> 1, wn = w & 1;
  const int ml = lane & 15, qd = lane >> 4;
  const int m0 = blockIdx.y * 128, n0 = blockIdx.x * 128;

  float4v acc[4][4];
  float4v z = {0.f, 0.f, 0.f, 0.f};
#pragma unroll
  for (int i = 0; i < 4; ++i)
#pragma unroll
    for (int j = 0; j < 4; ++j) acc[i][j] = z;

  const _Float16* Ap = A + (size_t)m0 * 256;
  const _Float16* Bp = Bw + (size_t)n0 * 256;
  const int gr = w * 64 + lane;
  const int row0 = gr >> 2, kb = gr & 3;

  for (int kt = 0; kt < 8; ++kt) {
    int k0 = kt * 32;
    gload_lds16(Ap + row0 * 256 + k0 + kb * 8, Ash + (size_t)(w * 64) * 8);
    gload_lds16(Ap + (row0 + 64) * 256 + k0 + kb * 8, Ash + (size_t)(256 + w * 64) * 8);
    gload_lds16(Bp + row0 * 256 + k0 + kb * 8, Bsh + (size_t)(w * 64) * 8);
    gload_lds16(Bp + (row0 + 64) * 256 + k0 + kb * 8, Bsh + (size_t)(256 + w * 64) * 8);
    __syncthreads();
    half8 af[4], bf[4];
#pragma unroll
    for (int im = 0; im < 4; ++im) {
      af[im] = *(const half8*)(Ash + (wm * 64 + im * 16 + ml) * 32 + qd * 8);
      bf[im] = *(const half8*)(Bsh + (wn * 64 + im * 16 + ml) * 32 + qd * 8);
    }
#pragma unroll
    for (int im = 0; im < 4; ++im)
#pragma unroll
      for (int in = 0; in < 4; ++in)
        acc[im][in] = __builtin_amdgcn_mfma_f32_16x16x32_f16(af[im], bf[in], acc[im][in], 0, 0, 0);
    __syncthreads();
  }

#pragma unroll
  for (int im = 0; im < 4; ++im) {
    int rowr0 = m0 + wm * 64 + im * 16 + qd * 4;
#pragma unroll
    for (int in = 0; in < 4; ++in) {
      int col = n0 + wn * 64 + in * 16 + ml;
      int s = col >> 8, h = (col >> 5) & 7, j = col & 31;
      _Float16* dst = s ? ko : qo;
#pragma unroll
      for (int r = 0; r < 4; ++r) {
        int rowr = rowr0 + r;
        int b = rowr >> 13, n = rowr & 8191;
        int t = n >> 10, yx = n & 1023;
        int p = b * 64 + h * 8 + t;
        dst[((size_t)p * 1024 + yx) * 32 + j] = (_Float16)acc[im][in][r];
      }
    }
  }
}

// ---- correlation via banded MFMA + normalize + (corr @ w_corr^T + b_corr) fused ----
// grid: 512 volumes * 4 tiles of 16x16; block 256 (4 waves); LDS 76800B -> 2 blocks/CU.
// LDS layout (halfs): [0,15488) k-tile [22 rows][22 cols][32 ch] linear
//                     [15488,35968) corr matrix [256 pos][80] (cols 0..48 taps, 49=1.0 bias, 50..63=0)
//                     [35968,38016) w_corr fp16 [32 d][64 k]
//                     [38016,38400) dump strip for invalid extraction lanes
__global__ __launch_bounds__(256, 2)
void corr_kernel(const _Float16* __restrict__ q16, const _Float16* __restrict__ k16,
                 const float* __restrict__ wcorr, const float* __restrict__ bcorr,
                 _Float16* __restrict__ outp) {
  __shared__ __align__(16) _Float16 S[38400];
  _Float16* kt = S;
  _Float16* corrh = S + 15488;
  _Float16* wch = S + 35968;
  constexpr int DUMP = 22528;  // dump offset in corrh half-units -> S+38016

  const int tid = threadIdx.x;
  const int bx = blockIdx.x;
  const int p = bx >> 2, tile = bx & 3;
  const int y0 = (tile >> 1) * 16, x0 = (tile & 1) * 16;
  const int b = p >> 6, h = (p >> 3) & 7, t = p & 7;
  const int pk = (t < 7) ? p + 1 : p;

  const int lane = tid & 63, w = tid >> 6;
  const int ml = lane & 15, qd = lane >> 4;

  // ---- A-fragments: 4 q rows per wave, straight from global (issued early) ----
  // layout: lane holds A[row=ml][k=qd*8..qd*8+7] = q position (y0+yy, x0+ml), channels qd*8..
  const _Float16* qbase = q16 + (size_t)p * 32768;
  half8 afrag[4];
#pragma unroll
  for (int yi = 0; yi < 4; ++yi) {
    int yy = 4 * w + yi;
    afrag[yi] = *(const half8*)(qbase + ((size_t)(y0 + yy) * 32 + (x0 + ml)) * 32 + qd * 8);
  }

  // ---- stage w_corr (fp16, K padded to 64 with bias folded at k=49) ----
  for (int idx = tid; idx < 2048; idx += 256) {
    int d = idx >> 6, kk = idx & 63;
    float v = (kk < 49) ? wcorr[d * 49 + kk] : (kk == 49 ? bcorr[d] : 0.f);
    wch[idx] = (_Float16)v;
  }

  // ---- stage k tile 22x22 vectors of 32 halfs, LINEAR layout, zero-padded borders ----
  const _Float16* kbase = k16 + (size_t)pk * 32768;
#pragma unroll
  for (int i = 0; i < 8; ++i) {
    int g = tid + i * 256;
    if (g < 1936) {
      int vec = g >> 2, part = g & 3;
      int ky = vec / 22, kx = vec - ky * 22;
      int gy = y0 + ky - 3, gx = x0 + kx - 3;
      uint4 val = make_uint4(0u, 0u, 0u, 0u);
      if (gy >= 0 && gy < 32 && gx >= 0 && gx < 32)
        val = *(const uint4*)(kbase + ((size_t)gy * 32 + gx) * 32 + part * 8);
      *(uint4*)(kt + (size_t)g * 8) = val;
    }
  }

  // ---- normalize q A-fragments in-register (reduce sumsq across the 4 qd lanes) ----
#pragma unroll
  for (int yi = 0; yi < 4; ++yi) {
    unsigned* au = (unsigned*)&afrag[yi];
    float ss = 0.f;
#pragma unroll
    for (int e = 0; e < 4; ++e) ss = dot2acc(au[e], au[e], ss);
    ss += __shfl_xor(ss, 16);
    ss += __shfl_xor(ss, 32);
    float sc = 1.f / fmaxf(sqrtf(ss), 1e-12f);
#pragma unroll
    for (int e = 0; e < 4; ++e) au[e] = hscale(au[e], sc);
  }

  // ---- prefill corr matrix cols 48..63 of own row: [49]=1.0 (bias), rest 0 ----
  {
    uint4 pat = make_uint4(0x3C000000u, 0u, 0u, 0u);  // halfs: 0, 1.0, 0,0,0,0,0,0
    uint4 zz = make_uint4(0u, 0u, 0u, 0u);
    *(uint4*)(corrh + (size_t)tid * 80 + 48) = pat;
    *(uint4*)(corrh + (size_t)tid * 80 + 56) = zz;
  }

  __syncthreads();

  // ---- normalize k vectors in LDS: 4-lane teams, consecutive granules (conflict-free) ----
#pragma unroll
  for (int i = 0; i < 8; ++i) {
    int g = tid + i * 256;
    if (g < 1936) {
      uint4 val = *(const uint4*)(kt + (size_t)g * 8);
      unsigned* u = (unsigned*)&val;
      float ss = 0.f;
#pragma unroll
      for (int e = 0; e < 4; ++e) ss = dot2acc(u[e], u[e], ss);
      ss += __shfl_xor(ss, 1);
      ss += __shfl_xor(ss, 2);
      float sc = 1.f / fmaxf(sqrtf(ss), 1e-12f);
#pragma unroll
      for (int e = 0; e < 4; ++e) u[e] = hscale(u[e], sc);
      *(uint4*)(kt + (size_t)g * 8) = val;
    }
  }
  __syncthreads();

  // ---- banded MFMA: wave w owns q rows yy=4w..4w+3; k rows kr=4w..4w+9 ----
  // D layout (verified by gemm epilogue): row(pos x)=qd*4+r, col(kcol)=ml(+16*nt)
  // dx = kcol - x = ml + 16*nt - 4*qd - r ; valid iff 0<=dx<=6 (also prunes kcol>21 garbage)
  // corr idx = (yy*16 + 4*qd + r)*80 + dy*7 + dx
  //          = [5120*w + 320*qd + (ml-4*qd)] + [1280*yi + 7*dy + 79*r + 16*nt]
  const int bdx = ml - 4 * qd;
  const int lanebase = 5120 * w + 320 * qd + bdx;
  float4v z = {0.f, 0.f, 0.f, 0.f};
#pragma unroll
  for (int kri = 0; kri < 10; ++kri) {
    int kr = 4 * w + kri;
    half8 bf0 = *(const half8*)(kt + ((size_t)kr * 22 + ml) * 32 + qd * 8);
    half8 bf1 = *(const half8*)(kt + ((size_t)kr * 22 + 16 + ml) * 32 + qd * 8);
#pragma unroll
    for (int yi = 0; yi < 4; ++yi) {
      int dy = kri - yi;
      if (dy < 0 || dy > 6) continue;
      float4v r0 = __builtin_amdgcn_mfma_f32_16x16x32_f16(afrag[yi], bf0, z, 0, 0, 0);
      float4v r1 = __builtin_amdgcn_mfma_f32_16x16x32_f16(afrag[yi], bf1, z, 0, 0, 0);
#pragma unroll
      for (int nt = 0; nt < 2; ++nt)
#pragma unroll
        for (int r = 0; r < 4; ++r) {
          int dx = bdx + (16 * nt - r);
          bool ok = (unsigned)dx <= 6u;
          int idx = lanebase + (1280 * yi + 7 * dy + 79 * r + 16 * nt);
          int off = ok ? idx : (DUMP + lane);
          corrh[off] = (_Float16)((nt ? r1 : r0)[r]);
        }
    }
  }
  __syncthreads();

  // ---- epilogue MFMA: (256 pos x 64k) @ (64k x 32d); wave w -> rows 64w..64w+63 ----
  float4v vacc[4][2];
#pragma unroll
  for (int im = 0; im < 4; ++im) { vacc[im][0] = z; vacc[im][1] = z; }
#pragma unroll
  for (int ks = 0; ks < 2; ++ks) {
    half8 bfrag[2];
#pragma unroll
    for (int nt = 0; nt < 2; ++nt)
      bfrag[nt] = *(const half8*)(wch + (nt * 16 + ml) * 64 + ks * 32 + qd * 8);
#pragma unroll
    for (int im = 0; im < 4; ++im) {
      half8 afr = *(const half8*)(corrh + (size_t)(w * 64 + im * 16 + ml) * 80 + ks * 32 + qd * 8);
#pragma unroll
      for (int nt = 0; nt < 2; ++nt)
        vacc[im][nt] = __builtin_amdgcn_mfma_f32_16x16x32_f16(afr, bfrag[nt], vacc[im][nt], 0, 0, 0);
    }
  }

  // ---- write v -> outpre[b, n, h*32+d] fp16 (bias already folded via K=49 column) ----
#pragma unroll
  for (int im = 0; im < 4; ++im) {
#pragma unroll
    for (int nt = 0; nt < 2; ++nt) {
      int d = nt * 16 + ml;
#pragma unroll
      for (int r = 0; r < 4; ++r) {
        int pos = w * 64 + im * 16 + qd * 4 + r;
        int py = pos >> 4, px = pos & 15;
        int n = t * 1024 + (y0 + py) * 32 + (x0 + px);
        outp[(((size_t)b * 8192 + n) << 8) + h * 32 + d] = (_Float16)vacc[im][nt][r];
      }
    }
  }
}

// ---- proj GEMM: out = op16 @ wproj16^T + b_proj (fp32 out) ----
__global__ __launch_bounds__(256, 2)
void gemm_proj(const _Float16* __restrict__ A, const _Float16* __restrict__ Bw,
               const float* __restrict__ bp, float* __restrict__ out) {
  __shared__ _Float16 Ash[4096];
  __shared__ _Float16 Bsh[4096];
  const int tid = threadIdx.x;
  const int lane = tid & 63, w = tid >> 6;
  const int wm = w >> 1, wn = w & 1;
  const int ml = lane & 15, qd = lane >> 4;
  const int m0 = blockIdx.y * 128, n0 = blockIdx.x * 128;

  float4v acc[4][4];
  float4v z = {0.f, 0.f, 0.f, 0.f};
#pragma unroll
  for (int i = 0; i < 4; ++i)
#pragma unroll
    for (int j = 0; j < 4; ++j) acc[i][j] = z;

  const _Float16* Ap = A + (size_t)m0 * 256;
  const _Float16* Bp = Bw + (size_t)n0 * 256;
  const int gr = w * 64 + lane;
  const int row0 = gr >> 2, kb = gr & 3;

  for (int kt = 0; kt < 8; ++kt) {
    int k0 = kt * 32;
    gload_lds16(Ap + row0 * 256 + k0 + kb * 8, Ash + (size_t)(w * 64) * 8);
    gload_lds16(Ap + (row0 + 64) * 256 + k0 + kb * 8, Ash + (size_t)(256 + w * 64) * 8);
    gload_lds16(Bp + row0 * 256 + k0 + kb * 8, Bsh + (size_t)(w * 64) * 8);
    gload_lds16(Bp + (row0 + 64) * 256 + k0 + kb * 8, Bsh + (size_t)(256 + w * 64) * 8);
    __syncthreads();
    half8 af[4], bf[4];
#pragma unroll
    for (int im = 0; im < 4; ++im) {
      af[im] = *(const half8*)(Ash + (wm * 64 + im * 16 + ml) * 32 + qd * 8);
      bf[im] = *(const half8*)(Bsh + (wn * 64 + im * 16 + ml) * 32 + qd * 8);
    }
#pragma unroll
    for (int im = 0; im < 4; ++im)
#pragma unroll
      for (int in = 0; in < 4; ++in)
        acc[im][in] = __builtin_amdgcn_mfma_f32_16x16x32_f16(af[im], bf[in], acc[im][in], 0, 0, 0);
    __syncthreads();
  }

#pragma unroll
  for (int im = 0; im < 4; ++im) {
    int rowr0 = m0 + wm * 64 + im * 16 + qd * 4;
#pragma unroll
    for (int in = 0; in < 4; ++in) {
      int col = n0 + wn * 64 + in * 16 + ml;
      float bias = bp[col];
#pragma unroll
      for (int r = 0; r < 4; ++r)
        out[(size_t)(rowr0 + r) * 256 + col] = acc[im][in][r] + bias;
    }
  }
}

extern "C" void kernel_launch(void* const* d_in, const int* in_sizes, int n_in,
                              void* d_out, int out_size, void* d_ws, size_t ws_size,
                              hipStream_t stream) {
  const float* x      = (const float*)d_in[0];
  const float* w_qk   = (const float*)d_in[1];
  const float* w_corr = (const float*)d_in[2];
  const float* b_corr = (const float*)d_in[3];
  const float* w_proj = (const float*)d_in[4];
  const float* b_proj = (const float*)d_in[5];
  float* out = (float*)d_out;

  char* ws = (char*)d_ws;
  _Float16* x16   = (_Float16*)(ws);
  _Float16* q16   = (_Float16*)(ws + 33554432);
  _Float16* k16   = (_Float16*)(ws + 67108864);
  _Float16* op16  = (_Float16*)(ws + 100663296);
  _Float16* wqk16 = (_Float16*)(ws + 134217728);
  _Float16* wpj16 = (_Float16*)(ws + 134479872);

  cvt_all<<<16576, 256, 0, stream>>>((const float4*)x, (const float4*)w_qk, (const float4*)w_proj,
                                     (ushort4*)x16, (ushort4*)wqk16, (ushort4*)wpj16);
  gemm_qk<<<dim3(4, 512), 256, 0, stream>>>(x16, wqk16, q16, k16);
  corr_kernel<<<2048, 256, 0, stream>>>(q16, k16, w_corr, b_corr, op16);
  gemm_proj<<<dim3(2, 512), 256, 0, stream>>>(op16, wpj16, b_proj, out);
}